// Round 13
// baseline (248.898 us; speedup 1.0000x reference)
//
#include <hip/hip_runtime.h>
#include <hip/hip_bf16.h>

#define LN_EPS 1e-5f

typedef __attribute__((ext_vector_type(8))) short bf16x8_t;
typedef __attribute__((ext_vector_type(4))) float f32x4_t;
typedef __attribute__((ext_vector_type(4))) unsigned short u16x4_t;

#define MFMA32(a, b, c) __builtin_amdgcn_mfma_f32_16x16x32_bf16(a, b, c, 0, 0, 0)

// Guaranteed-native exp2 (single v_exp_f32) — verified win in R9.
__device__ inline float fast_exp2(float x) {
#if __has_builtin(__builtin_amdgcn_exp2f)
    return __builtin_amdgcn_exp2f(x);
#else
    float r;
    asm volatile("v_exp_f32 %0, %1\n\ts_nop 0" : "=v"(r) : "v"(x));
    return r;
#endif
}

__device__ inline unsigned short f2bf(float f) {
    union { float f; unsigned int u; } v; v.f = f;
    unsigned int r = v.u + 0x7fffu + ((v.u >> 16) & 1u);
    return (unsigned short)(r >> 16);
}

__device__ inline u16x4_t pk4(float a, float b, float c, float d) {
    union { u16x4_t v; __hip_bfloat162 h[2]; } u;
    u.h[0] = __float22bfloat162_rn(float2{a, b});
    u.h[1] = __float22bfloat162_rn(float2{c, d});
    return u.v;
}
__device__ inline bf16x8_t pk8(float4 a, float4 b) {
    union { bf16x8_t v; __hip_bfloat162 h[4]; } u;
    u.h[0] = __float22bfloat162_rn(float2{a.x, a.y});
    u.h[1] = __float22bfloat162_rn(float2{a.z, a.w});
    u.h[2] = __float22bfloat162_rn(float2{b.x, b.y});
    u.h[3] = __float22bfloat162_rn(float2{b.z, b.w});
    return u.v;
}

// Fragment-layout index for [ROWS][KD] stored as MFMA fragments:
// tile (row>>4, k>>5) = 512 contiguous u16; lane=((k>>3)&3)*16+(row&15), j=k&7.
__device__ inline size_t fragidx(int row, int k, int KC) {
    return ((size_t)((row >> 4) * KC + (k >> 5))) * 512 +
           (((k >> 3) & 3) * 16 + (row & 15)) * 8 + (k & 7);
}

// ---------------------------------------------------------------------------
__global__ void k_prep_w(const float* __restrict__ qW, const float* __restrict__ kvW,
                         const float* __restrict__ projW, const float* __restrict__ srW,
                         unsigned short* __restrict__ qWs, unsigned short* __restrict__ kvWs,
                         unsigned short* __restrict__ projWs, unsigned short* __restrict__ srWs) {
    int i = blockIdx.x * 256 + threadIdx.x;
    if (i < 16384) {
        int n = i & 127, k = i >> 7;
        qWs[fragidx(n, k, 4)] = f2bf(qW[k * 128 + n]);
    } else if (i < 49152) {
        int j = i - 16384; int n = j & 255, k = j >> 8;
        kvWs[fragidx(n, k, 4)] = f2bf(kvW[k * 256 + n]);
    } else if (i < 65536) {
        int j = i - 49152; int n = j & 127, k = j >> 7;
        projWs[fragidx(n, k, 4)] = f2bf(projW[k * 128 + n]);
    } else {
        int j = i - 65536; int n = j >> 9, rem = j & 511, q = rem >> 7, c = rem & 127;
        srWs[fragidx(n, q * 128 + c, 16)] = f2bf(srW[n * 512 + c * 4 + q]);
    }
}

// ---------------------------------------------------------------------------
// Fused SR-conv + bias + LayerNorm + kv-projection (unchanged from R11/R12).
#define XPAD 132
__global__ __launch_bounds__(256)
void k_convkv(const float* __restrict__ x, const unsigned short* __restrict__ srWs,
              const float* __restrict__ srb, const float* __restrict__ lnW,
              const float* __restrict__ lnB, const unsigned short* __restrict__ kvWs,
              const float* __restrict__ kvb, unsigned short* __restrict__ ksw,
              unsigned short* __restrict__ vls) {
    const int t = threadIdx.x, w = t >> 6, lane = t & 63;
    const int col = lane & 15, quad = lane >> 4;
    const int RT = blockIdx.x;

    __shared__ unsigned short xl[64 * XPAD];
    __shared__ unsigned short xs[4 * 512];
    __shared__ float lnred[4][16][2];

    const int pb = RT >> 7, phf = (RT >> 6) & 1;
    const int oy = (RT >> 1) & 31, ox0 = (RT & 1) * 16;
    const int n0 = phf * 4096 + 2 * oy * 64 + 2 * ox0;
    #pragma unroll
    for (int it = 0; it < 8; it++) {
        int idx = it * 256 + t;
        int chunk = idx >> 10;
        int rr = (idx >> 5) & 31;
        int c4 = idx & 31;
        float4 v = *(const float4*)(x + ((size_t)(pb * 8192 + n0 + chunk * 64 + rr)) * 128 + c4 * 4);
        *(u16x4_t*)(xl + (chunk * 32 + rr) * XPAD + c4 * 4) = pk4(v.x, v.y, v.z, v.w);
    }
    __syncthreads();

    f32x4_t acc[2] = {};
    {
        const unsigned short* wp = srWs + lane * 8;
        #pragma unroll
        for (int kc = 0; kc < 16; kc++) {
            const int q = kc >> 2, cg = kc & 3;
            const int r = (q >> 1) * 32 + 2 * col + (q & 1);
            bf16x8_t xb = *(const bf16x8_t*)(xl + r * XPAD + cg * 32 + quad * 8);
            #pragma unroll
            for (int jj = 0; jj < 2; jj++) {
                bf16x8_t wf = *(const bf16x8_t*)(wp + (size_t)((w * 2 + jj) * 16 + kc) * 512);
                acc[jj] = MFMA32(wf, xb, acc[jj]);
            }
        }
    }
    float s = 0.f, ss = 0.f;
    #pragma unroll
    for (int jj = 0; jj < 2; jj++) {
        float4 bs = *(const float4*)(srb + (w * 2 + jj) * 16 + quad * 4);
        acc[jj][0] += bs.x; acc[jj][1] += bs.y; acc[jj][2] += bs.z; acc[jj][3] += bs.w;
        #pragma unroll
        for (int r = 0; r < 4; r++) { float v = acc[jj][r]; s += v; ss += v * v; }
    }
    s += __shfl_xor(s, 16, 64);  s += __shfl_xor(s, 32, 64);
    ss += __shfl_xor(ss, 16, 64); ss += __shfl_xor(ss, 32, 64);
    if (lane < 16) { lnred[w][lane][0] = s; lnred[w][lane][1] = ss; }
    __syncthreads();
    float stot = 0.f, sstot = 0.f;
    #pragma unroll
    for (int ww = 0; ww < 4; ww++) { stot += lnred[ww][col][0]; sstot += lnred[ww][col][1]; }
    float mean = stot * (1.0f / 128.0f);
    float var = sstot * (1.0f / 128.0f) - mean * mean;
    float rs = rsqrtf(var + LN_EPS);
    #pragma unroll
    for (int jj = 0; jj < 2; jj++) {
        int f0 = (w * 2 + jj) * 16 + quad * 4;
        float4 g = *(const float4*)(lnW + f0);
        float4 be = *(const float4*)(lnB + f0);
        u16x4_t o = pk4((acc[jj][0] - mean) * rs * g.x + be.x,
                        (acc[jj][1] - mean) * rs * g.y + be.y,
                        (acc[jj][2] - mean) * rs * g.z + be.z,
                        (acc[jj][3] - mean) * rs * g.w + be.w);
        *(u16x4_t*)(xs + ((size_t)(f0 >> 5)) * 512 +
                    (((f0 >> 3) & 3) * 16 + col) * 8 + (f0 & 7)) = o;
    }
    __syncthreads();
    bf16x8_t xf[4];
    #pragma unroll
    for (int kc = 0; kc < 4; kc++)
        xf[kc] = *(const bf16x8_t*)(xs + (size_t)kc * 512 + lane * 8);
    const int p0 = RT * 16;
    const int bb = p0 >> 11;
    #pragma unroll
    for (int jj = 0; jj < 2; jj++) {
        const int nt = w * 2 + jj;
        f32x4_t aK = {};
        #pragma unroll
        for (int kc = 0; kc < 4; kc++) {
            bf16x8_t wf = *(const bf16x8_t*)(kvWs + (size_t)(nt * 4 + kc) * 512 + lane * 8);
            aK = MFMA32(wf, xf[kc], aK);
        }
        float4 bs = *(const float4*)(kvb + nt * 16 + quad * 4);
        int m = (p0 + col) & 2047;
        int bh = bb * 2 + (nt >> 2);
        int d0 = (nt & 3) * 16 + quad * 4;
        u16x4_t o = pk4(aK[0] + bs.x, aK[1] + bs.y, aK[2] + bs.z, aK[3] + bs.w);
        *(u16x4_t*)(ksw + ((size_t)(bh * 128 + (m >> 4)) * 2 + (d0 >> 5)) * 512 +
                    (((d0 >> 3) & 3) * 16 + (m & 15)) * 8 + (d0 & 7)) = o;
    }
    #pragma unroll
    for (int jj = 0; jj < 2; jj++) {
        const int nt = w * 2 + jj;
        f32x4_t aV = {};
        #pragma unroll
        for (int kc = 0; kc < 4; kc++) {
            bf16x8_t wf = *(const bf16x8_t*)(kvWs + (size_t)((8 + nt) * 4 + kc) * 512 + lane * 8);
            aV = MFMA32(xf[kc], wf, aV);
        }
        int fv = nt * 16 + col;
        int h = fv >> 6, dd = fv & 63;
        float bv = kvb[128 + fv];
        int m0 = (p0 + quad * 4) & 2047;
        int bh = bb * 2 + h;
        int kt = m0 >> 6;
        int tt = (m0 >> 5) & 1;
        int base = m0 & 31;
        int quad_b = base >> 3, j0 = base & 7;
        u16x4_t o = pk4(aV[0] + bv, aV[1] + bv, aV[2] + bv, aV[3] + bv);
        *(u16x4_t*)(vls + (((size_t)((bh * 32 + kt) * 4 + (dd >> 4)) * 2 + tt) * 512) +
                    (quad_b * 16 + (dd & 15)) * 8 + j0) = o;
    }
}

// ---------------------------------------------------------------------------
// Fused q-proj + attention + out-proj. R12 structure (64 q/wave key-split,
// all-MFMA32, native exp2) with an ALIASED LDS ARENA (~35 KB vs 68 KB):
// Q-stage [0,16K) -> pls [0,16K) (per qp-pair, 2 qt live) -> O-rows [0,17.4K)
// + Ocomb [17.5K,34.9K) + lcomb. 4 blocks/CU -> 4 waves/SIMD (2x TLP).
// Block 256 = 4 waves (ks=w&1, h=w>>1); grid (64, 2, 4) = 512 blocks.
__global__ __launch_bounds__(256, 4)
void k_attn_f9(const float* __restrict__ x, const unsigned short* __restrict__ qWs,
               const float* __restrict__ qb, const unsigned short* __restrict__ ksw,
               const unsigned short* __restrict__ vls, const unsigned short* __restrict__ projWs,
               const float* __restrict__ projb, float* __restrict__ out) {
    const int blkx = blockIdx.x, mod = blockIdx.y, b = blockIdx.z;
    const int t = threadIdx.x, w = t >> 6, lane = t & 63;
    const int col = lane & 15, quad = lane >> 4;
    const int ks = w & 1, h = w >> 1;
    const int bh = b * 2 + h;
    const int qbase = mod * 4096 + blkx * 64;      // 64 queries per block

    __shared__ char arena[35200];
    unsigned short* qstage = (unsigned short*)arena;            // [0, 16K)
    unsigned short* pw     = (unsigned short*)arena + w * 2048; // pls, 4KB/wave
    unsigned short* rows   = (unsigned short*)arena;            // [0, 17.4K)
    float* Ocomb = (float*)(arena + 17536);                     // 64*68*4 B
    float* lcomb = (float*)(arena + 34944);                     // 256 B

    // ---- q-proj: wave (ks,h) computes q-tiles {2ks, 2ks+1} of head h
    const float sc = 0.125f * 1.44269504089f;
    #pragma unroll
    for (int qtl = 0; qtl < 2; qtl++) {
        const int qt = ks * 2 + qtl;
        const float* xrow = x + ((size_t)b * 8192 + qbase + qt * 16 + col) * 128;
        f32x4_t acc[4] = {};
        #pragma unroll
        for (int kc = 0; kc < 4; kc++) {
            float4 xa = *(const float4*)(xrow + kc * 32 + quad * 8);
            float4 xb2 = *(const float4*)(xrow + kc * 32 + quad * 8 + 4);
            bf16x8_t xf = pk8(xa, xb2);
            #pragma unroll
            for (int j = 0; j < 4; j++) {
                bf16x8_t wf = *(const bf16x8_t*)(qWs + (size_t)((h * 4 + j) * 4 + kc) * 512 + lane * 8);
                acc[j] = MFMA32(wf, xf, acc[j]);
            }
        }
        #pragma unroll
        for (int j = 0; j < 4; j++) {
            float4 bs = *(const float4*)(qb + h * 64 + j * 16 + quad * 4);
            u16x4_t o = pk4((acc[j][0] + bs.x) * sc, (acc[j][1] + bs.y) * sc,
                            (acc[j][2] + bs.z) * sc, (acc[j][3] + bs.w) * sc);
            *(u16x4_t*)(qstage + (size_t)h * 4096 + ((size_t)(qt * 2 + (j >> 1))) * 512 +
                        (((j & 1) * 2 + (quad >> 1)) * 16 + col) * 8 + (quad & 1) * 4) = o;
        }
    }
    __syncthreads();
    bf16x8_t qf[4][2];
    #pragma unroll
    for (int qt = 0; qt < 4; qt++)
        #pragma unroll
        for (int kc = 0; kc < 2; kc++)
            qf[qt][kc] = *(const bf16x8_t*)(qstage + (size_t)h * 4096 +
                                            (size_t)(qt * 2 + kc) * 512 + lane * 8);
    __syncthreads();   // Q in regs everywhere; arena region reusable as pls

    const unsigned short* kp0 =
        ksw + ((size_t)(bh * 128 + (1 - mod) * 64) * 2) * 512 + lane * 8;
    const unsigned short* vp0 =
        vls + ((size_t)((bh * 32 + (1 - mod) * 16) * 8)) * 512 + lane * 8;
    const bf16x8_t ones8 = { 0x3F80, 0x3F80, 0x3F80, 0x3F80,
                             0x3F80, 0x3F80, 0x3F80, 0x3F80 };

    f32x4_t O[4][4] = {};
    f32x4_t accl[4] = {};

    for (int kti = 0; kti < 8; kti++) {
        const int kt = ks * 8 + kti;
        bf16x8_t kf[8], vf[8];
        #pragma unroll
        for (int i = 0; i < 8; i++) {
            kf[i] = *(const bf16x8_t*)(kp0 + (size_t)(kt * 8 + i) * 512);
            vf[i] = *(const bf16x8_t*)(vp0 + (size_t)(kt * 8 + i) * 512);
        }
        // process q-tiles in pairs; pls holds only the live pair
        #pragma unroll
        for (int qp = 0; qp < 2; qp++) {
            f32x4_t ST[2][4];
            #pragma unroll
            for (int qtl = 0; qtl < 2; qtl++) {
                const int qt = qp * 2 + qtl;
                #pragma unroll
                for (int nb = 0; nb < 4; nb++) {
                    f32x4_t sA = {};
                    sA = MFMA32(kf[nb * 2 + 0], qf[qt][0], sA);
                    sA = MFMA32(kf[nb * 2 + 1], qf[qt][1], sA);
                    ST[qtl][nb] = sA;
                }
            }
            // exp2 -> P into LDS K32 A-frag layout (same-wave, no barrier)
            #pragma unroll
            for (int qtl = 0; qtl < 2; qtl++)
                #pragma unroll
                for (int nb = 0; nb < 4; nb++) {
                    u16x4_t pk = pk4(fast_exp2(ST[qtl][nb][0]), fast_exp2(ST[qtl][nb][1]),
                                     fast_exp2(ST[qtl][nb][2]), fast_exp2(ST[qtl][nb][3]));
                    *(u16x4_t*)(pw + qtl * 1024 + (nb >> 1) * 512 +
                                (((nb & 1) * 2 + (quad >> 1)) * 16 + col) * 8 + (quad & 1) * 4) = pk;
                }
            // P K32 A-frags -> l + PV (all MFMA32)
            #pragma unroll
            for (int qtl = 0; qtl < 2; qtl++) {
                const int qt = qp * 2 + qtl;
                bf16x8_t pf0 = *(const bf16x8_t*)(pw + qtl * 1024 + lane * 8);
                bf16x8_t pf1 = *(const bf16x8_t*)(pw + qtl * 1024 + 512 + lane * 8);
                accl[qt] = MFMA32(pf0, ones8, accl[qt]);
                accl[qt] = MFMA32(pf1, ones8, accl[qt]);
                #pragma unroll
                for (int dt = 0; dt < 4; dt++) {
                    O[qt][dt] = MFMA32(pf0, vf[dt * 2 + 0], O[qt][dt]);
                    O[qt][dt] = MFMA32(pf1, vf[dt * 2 + 1], O[qt][dt]);
                }
            }
        }
    }
    __syncthreads();   // all waves done with pls; arena reusable for combine

    // ---- key-split combine (pure add; per-head sequential fp32 LDS)
    #pragma unroll
    for (int hp = 0; hp < 2; hp++) {
        if (h == hp && ks == 1) {
            #pragma unroll
            for (int qt = 0; qt < 4; qt++)
                #pragma unroll
                for (int r = 0; r < 4; r++) {
                    int qrow = qt * 16 + quad * 4 + r;
                    #pragma unroll
                    for (int dt = 0; dt < 4; dt++)
                        Ocomb[qrow * 68 + dt * 16 + col] = O[qt][dt][r];
                    if (col == 0) lcomb[qrow] = accl[qt][r];
                }
        }
        __syncthreads();
        if (h == hp && ks == 0) {
            #pragma unroll
            for (int qt = 0; qt < 4; qt++)
                #pragma unroll
                for (int r = 0; r < 4; r++) {
                    int qrow = qt * 16 + quad * 4 + r;
                    float lt = accl[qt][r] + lcomb[qrow];
                    float rl = 1.0f / lt;
                    #pragma unroll
                    for (int dt = 0; dt < 4; dt++) {
                        float ov = O[qt][dt][r] + Ocomb[qrow * 68 + dt * 16 + col];
                        rows[qrow * 136 + hp * 64 + dt * 16 + col] = f2bf(ov * rl);
                    }
                }
        }
        __syncthreads();
    }

    // ---- out-proj: wave w -> q-tile w (16 queries, all 128 features)
    {
        const int qt2 = w;
        bf16x8_t ob[4];
        #pragma unroll
        for (int kc = 0; kc < 4; kc++)
            ob[kc] = *(const bf16x8_t*)(rows + (size_t)(qt2 * 16 + col) * 136 + kc * 32 + quad * 8);
        f32x4_t acc[8];
        #pragma unroll
        for (int j = 0; j < 8; j++) acc[j] = f32x4_t{};
        #pragma unroll
        for (int kc = 0; kc < 4; kc++)
            #pragma unroll
            for (int j = 0; j < 8; j++) {
                bf16x8_t wf = *(const bf16x8_t*)(projWs + (size_t)(j * 4 + kc) * 512 + lane * 8);
                acc[j] = MFMA32(wf, ob[kc], acc[j]);
            }
        const int n = b * 8192 + qbase + qt2 * 16 + col;
        #pragma unroll
        for (int j = 0; j < 8; j++) {
            int f0 = j * 16 + quad * 4;
            float4 bs = *(const float4*)(projb + f0);
            float4 o = { acc[j][0] + bs.x, acc[j][1] + bs.y,
                         acc[j][2] + bs.z, acc[j][3] + bs.w };
            *(float4*)(out + (size_t)n * 128 + f0) = o;
        }
    }
}

// ---------------------------------------------------------------------------
extern "C" void kernel_launch(void* const* d_in, const int* in_sizes, int n_in,
                              void* d_out, int out_size, void* d_ws, size_t ws_size,
                              hipStream_t stream) {
    const float* x     = (const float*)d_in[0];
    const float* qW    = (const float*)d_in[1];
    const float* qb    = (const float*)d_in[2];
    const float* kvW   = (const float*)d_in[3];
    const float* kvb   = (const float*)d_in[4];
    const float* projW = (const float*)d_in[5];
    const float* projb = (const float*)d_in[6];
    const float* srW   = (const float*)d_in[7];
    const float* srb   = (const float*)d_in[8];
    const float* lnW   = (const float*)d_in[9];
    const float* lnB   = (const float*)d_in[10];

    char* ws = (char*)d_ws;
    unsigned short* qWs    = (unsigned short*)(ws + 0);         // 32 KB
    unsigned short* kvWs   = (unsigned short*)(ws + 32768);     // 64 KB
    unsigned short* projWs = (unsigned short*)(ws + 98304);     // 32 KB
    unsigned short* srWs   = (unsigned short*)(ws + 131072);    // 128 KB
    unsigned short* ksw    = (unsigned short*)(ws + 262144);    // 2 MB
    unsigned short* vls    = (unsigned short*)(ws + 2359296);   // 2 MB

    k_prep_w<<<dim3(512), dim3(256), 0, stream>>>(qW, kvW, projW, srW,
                                                  qWs, kvWs, projWs, srWs);
    k_convkv<<<dim3(512), dim3(256), 0, stream>>>(x, srWs, srb, lnW, lnB,
                                                  kvWs, kvb, ksw, vls);
    k_attn_f9<<<dim3(64, 2, 4), dim3(256), 0, stream>>>(x, qWs, qb, ksw, vls,
                                                        projWs, projb, (float*)d_out);
}

// Round 14
// 132.756 us; speedup vs baseline: 1.8748x; 1.8748x over previous
//
#include <hip/hip_runtime.h>
#include <hip/hip_bf16.h>

#define LN_EPS 1e-5f

typedef __attribute__((ext_vector_type(8))) short bf16x8_t;
typedef __attribute__((ext_vector_type(4))) float f32x4_t;
typedef __attribute__((ext_vector_type(4))) unsigned short u16x4_t;

#define MFMA32(a, b, c) __builtin_amdgcn_mfma_f32_16x16x32_bf16(a, b, c, 0, 0, 0)

// Guaranteed-native exp2 (single v_exp_f32) — verified win in R9.
__device__ inline float fast_exp2(float x) {
#if __has_builtin(__builtin_amdgcn_exp2f)
    return __builtin_amdgcn_exp2f(x);
#else
    float r;
    asm volatile("v_exp_f32 %0, %1\n\ts_nop 0" : "=v"(r) : "v"(x));
    return r;
#endif
}

__device__ inline unsigned short f2bf(float f) {
    union { float f; unsigned int u; } v; v.f = f;
    unsigned int r = v.u + 0x7fffu + ((v.u >> 16) & 1u);
    return (unsigned short)(r >> 16);
}

__device__ inline u16x4_t pk4(float a, float b, float c, float d) {
    union { u16x4_t v; __hip_bfloat162 h[2]; } u;
    u.h[0] = __float22bfloat162_rn(float2{a, b});
    u.h[1] = __float22bfloat162_rn(float2{c, d});
    return u.v;
}
__device__ inline bf16x8_t pk8(float4 a, float4 b) {
    union { bf16x8_t v; __hip_bfloat162 h[4]; } u;
    u.h[0] = __float22bfloat162_rn(float2{a.x, a.y});
    u.h[1] = __float22bfloat162_rn(float2{a.z, a.w});
    u.h[2] = __float22bfloat162_rn(float2{b.x, b.y});
    u.h[3] = __float22bfloat162_rn(float2{b.z, b.w});
    return u.v;
}

// Fragment-layout index for [ROWS][KD] stored as MFMA fragments:
// tile (row>>4, k>>5) = 512 contiguous u16; lane=((k>>3)&3)*16+(row&15), j=k&7.
__device__ inline size_t fragidx(int row, int k, int KC) {
    return ((size_t)((row >> 4) * KC + (k >> 5))) * 512 +
           (((k >> 3) & 3) * 16 + (row & 15)) * 8 + (k & 7);
}

// ---------------------------------------------------------------------------
__global__ void k_prep_w(const float* __restrict__ qW, const float* __restrict__ kvW,
                         const float* __restrict__ projW, const float* __restrict__ srW,
                         unsigned short* __restrict__ qWs, unsigned short* __restrict__ kvWs,
                         unsigned short* __restrict__ projWs, unsigned short* __restrict__ srWs) {
    int i = blockIdx.x * 256 + threadIdx.x;
    if (i < 16384) {
        int n = i & 127, k = i >> 7;
        qWs[fragidx(n, k, 4)] = f2bf(qW[k * 128 + n]);
    } else if (i < 49152) {
        int j = i - 16384; int n = j & 255, k = j >> 8;
        kvWs[fragidx(n, k, 4)] = f2bf(kvW[k * 256 + n]);
    } else if (i < 65536) {
        int j = i - 49152; int n = j & 127, k = j >> 7;
        projWs[fragidx(n, k, 4)] = f2bf(projW[k * 128 + n]);
    } else {
        int j = i - 65536; int n = j >> 9, rem = j & 511, q = rem >> 7, c = rem & 127;
        srWs[fragidx(n, q * 128 + c, 16)] = f2bf(srW[n * 512 + c * 4 + q]);
    }
}

// ---------------------------------------------------------------------------
// Fused SR-conv + bias + LayerNorm + kv-projection (unchanged from R11/R12).
#define XPAD 132
__global__ __launch_bounds__(256)
void k_convkv(const float* __restrict__ x, const unsigned short* __restrict__ srWs,
              const float* __restrict__ srb, const float* __restrict__ lnW,
              const float* __restrict__ lnB, const unsigned short* __restrict__ kvWs,
              const float* __restrict__ kvb, unsigned short* __restrict__ ksw,
              unsigned short* __restrict__ vls) {
    const int t = threadIdx.x, w = t >> 6, lane = t & 63;
    const int col = lane & 15, quad = lane >> 4;
    const int RT = blockIdx.x;

    __shared__ unsigned short xl[64 * XPAD];
    __shared__ unsigned short xs[4 * 512];
    __shared__ float lnred[4][16][2];

    const int pb = RT >> 7, phf = (RT >> 6) & 1;
    const int oy = (RT >> 1) & 31, ox0 = (RT & 1) * 16;
    const int n0 = phf * 4096 + 2 * oy * 64 + 2 * ox0;
    #pragma unroll
    for (int it = 0; it < 8; it++) {
        int idx = it * 256 + t;
        int chunk = idx >> 10;
        int rr = (idx >> 5) & 31;
        int c4 = idx & 31;
        float4 v = *(const float4*)(x + ((size_t)(pb * 8192 + n0 + chunk * 64 + rr)) * 128 + c4 * 4);
        *(u16x4_t*)(xl + (chunk * 32 + rr) * XPAD + c4 * 4) = pk4(v.x, v.y, v.z, v.w);
    }
    __syncthreads();

    f32x4_t acc[2] = {};
    {
        const unsigned short* wp = srWs + lane * 8;
        #pragma unroll
        for (int kc = 0; kc < 16; kc++) {
            const int q = kc >> 2, cg = kc & 3;
            const int r = (q >> 1) * 32 + 2 * col + (q & 1);
            bf16x8_t xb = *(const bf16x8_t*)(xl + r * XPAD + cg * 32 + quad * 8);
            #pragma unroll
            for (int jj = 0; jj < 2; jj++) {
                bf16x8_t wf = *(const bf16x8_t*)(wp + (size_t)((w * 2 + jj) * 16 + kc) * 512);
                acc[jj] = MFMA32(wf, xb, acc[jj]);
            }
        }
    }
    float s = 0.f, ss = 0.f;
    #pragma unroll
    for (int jj = 0; jj < 2; jj++) {
        float4 bs = *(const float4*)(srb + (w * 2 + jj) * 16 + quad * 4);
        acc[jj][0] += bs.x; acc[jj][1] += bs.y; acc[jj][2] += bs.z; acc[jj][3] += bs.w;
        #pragma unroll
        for (int r = 0; r < 4; r++) { float v = acc[jj][r]; s += v; ss += v * v; }
    }
    s += __shfl_xor(s, 16, 64);  s += __shfl_xor(s, 32, 64);
    ss += __shfl_xor(ss, 16, 64); ss += __shfl_xor(ss, 32, 64);
    if (lane < 16) { lnred[w][lane][0] = s; lnred[w][lane][1] = ss; }
    __syncthreads();
    float stot = 0.f, sstot = 0.f;
    #pragma unroll
    for (int ww = 0; ww < 4; ww++) { stot += lnred[ww][col][0]; sstot += lnred[ww][col][1]; }
    float mean = stot * (1.0f / 128.0f);
    float var = sstot * (1.0f / 128.0f) - mean * mean;
    float rs = rsqrtf(var + LN_EPS);
    #pragma unroll
    for (int jj = 0; jj < 2; jj++) {
        int f0 = (w * 2 + jj) * 16 + quad * 4;
        float4 g = *(const float4*)(lnW + f0);
        float4 be = *(const float4*)(lnB + f0);
        u16x4_t o = pk4((acc[jj][0] - mean) * rs * g.x + be.x,
                        (acc[jj][1] - mean) * rs * g.y + be.y,
                        (acc[jj][2] - mean) * rs * g.z + be.z,
                        (acc[jj][3] - mean) * rs * g.w + be.w);
        *(u16x4_t*)(xs + ((size_t)(f0 >> 5)) * 512 +
                    (((f0 >> 3) & 3) * 16 + col) * 8 + (f0 & 7)) = o;
    }
    __syncthreads();
    bf16x8_t xf[4];
    #pragma unroll
    for (int kc = 0; kc < 4; kc++)
        xf[kc] = *(const bf16x8_t*)(xs + (size_t)kc * 512 + lane * 8);
    const int p0 = RT * 16;
    const int bb = p0 >> 11;
    #pragma unroll
    for (int jj = 0; jj < 2; jj++) {
        const int nt = w * 2 + jj;
        f32x4_t aK = {};
        #pragma unroll
        for (int kc = 0; kc < 4; kc++) {
            bf16x8_t wf = *(const bf16x8_t*)(kvWs + (size_t)(nt * 4 + kc) * 512 + lane * 8);
            aK = MFMA32(wf, xf[kc], aK);
        }
        float4 bs = *(const float4*)(kvb + nt * 16 + quad * 4);
        int m = (p0 + col) & 2047;
        int bh = bb * 2 + (nt >> 2);
        int d0 = (nt & 3) * 16 + quad * 4;
        u16x4_t o = pk4(aK[0] + bs.x, aK[1] + bs.y, aK[2] + bs.z, aK[3] + bs.w);
        *(u16x4_t*)(ksw + ((size_t)(bh * 128 + (m >> 4)) * 2 + (d0 >> 5)) * 512 +
                    (((d0 >> 3) & 3) * 16 + (m & 15)) * 8 + (d0 & 7)) = o;
    }
    #pragma unroll
    for (int jj = 0; jj < 2; jj++) {
        const int nt = w * 2 + jj;
        f32x4_t aV = {};
        #pragma unroll
        for (int kc = 0; kc < 4; kc++) {
            bf16x8_t wf = *(const bf16x8_t*)(kvWs + (size_t)((8 + nt) * 4 + kc) * 512 + lane * 8);
            aV = MFMA32(xf[kc], wf, aV);
        }
        int fv = nt * 16 + col;
        int h = fv >> 6, dd = fv & 63;
        float bv = kvb[128 + fv];
        int m0 = (p0 + quad * 4) & 2047;
        int bh = bb * 2 + h;
        int kt = m0 >> 6;
        int tt = (m0 >> 5) & 1;
        int base = m0 & 31;
        int quad_b = base >> 3, j0 = base & 7;
        u16x4_t o = pk4(aV[0] + bv, aV[1] + bv, aV[2] + bv, aV[3] + bv);
        *(u16x4_t*)(vls + (((size_t)((bh * 32 + kt) * 4 + (dd >> 4)) * 2 + tt) * 512) +
                    (quad_b * 16 + (dd & 15)) * 8 + j0) = o;
    }
}

// ---------------------------------------------------------------------------
// Fused q-proj + attention + out-proj. R12 structure (64 q/wave key-split,
// all-MFMA32, native exp2) with the ALIASED LDS ARENA (~35 KB): Q-stage
// [0,16K) -> pls [0,16K) -> O-rows + Ocomb + lcomb. launch_bounds kept at
// (256,2): this is a MINIMUM for the allocator (R13's (256,4) forced VGPR=64
// and spilled everything — 262MB FETCH). At the natural ~120 VGPR, HW can
// still co-schedule 4 blocks/CU now that LDS fits.
// Block 256 = 4 waves (ks=w&1, h=w>>1); grid (64, 2, 4) = 512 blocks.
__global__ __launch_bounds__(256, 2)
void k_attn_f10(const float* __restrict__ x, const unsigned short* __restrict__ qWs,
                const float* __restrict__ qb, const unsigned short* __restrict__ ksw,
                const unsigned short* __restrict__ vls, const unsigned short* __restrict__ projWs,
                const float* __restrict__ projb, float* __restrict__ out) {
    const int blkx = blockIdx.x, mod = blockIdx.y, b = blockIdx.z;
    const int t = threadIdx.x, w = t >> 6, lane = t & 63;
    const int col = lane & 15, quad = lane >> 4;
    const int ks = w & 1, h = w >> 1;
    const int bh = b * 2 + h;
    const int qbase = mod * 4096 + blkx * 64;      // 64 queries per block

    __shared__ char arena[35200];
    unsigned short* qstage = (unsigned short*)arena;            // [0, 16K)
    unsigned short* pw     = (unsigned short*)arena + w * 2048; // pls, 4KB/wave
    unsigned short* rows   = (unsigned short*)arena;            // [0, 17.4K)
    float* Ocomb = (float*)(arena + 17536);                     // 64*68*4 B
    float* lcomb = (float*)(arena + 34944);                     // 256 B

    // ---- q-proj: wave (ks,h) computes q-tiles {2ks, 2ks+1} of head h
    const float sc = 0.125f * 1.44269504089f;
    #pragma unroll
    for (int qtl = 0; qtl < 2; qtl++) {
        const int qt = ks * 2 + qtl;
        const float* xrow = x + ((size_t)b * 8192 + qbase + qt * 16 + col) * 128;
        f32x4_t acc[4] = {};
        #pragma unroll
        for (int kc = 0; kc < 4; kc++) {
            float4 xa = *(const float4*)(xrow + kc * 32 + quad * 8);
            float4 xb2 = *(const float4*)(xrow + kc * 32 + quad * 8 + 4);
            bf16x8_t xf = pk8(xa, xb2);
            #pragma unroll
            for (int j = 0; j < 4; j++) {
                bf16x8_t wf = *(const bf16x8_t*)(qWs + (size_t)((h * 4 + j) * 4 + kc) * 512 + lane * 8);
                acc[j] = MFMA32(wf, xf, acc[j]);
            }
        }
        #pragma unroll
        for (int j = 0; j < 4; j++) {
            float4 bs = *(const float4*)(qb + h * 64 + j * 16 + quad * 4);
            u16x4_t o = pk4((acc[j][0] + bs.x) * sc, (acc[j][1] + bs.y) * sc,
                            (acc[j][2] + bs.z) * sc, (acc[j][3] + bs.w) * sc);
            *(u16x4_t*)(qstage + (size_t)h * 4096 + ((size_t)(qt * 2 + (j >> 1))) * 512 +
                        (((j & 1) * 2 + (quad >> 1)) * 16 + col) * 8 + (quad & 1) * 4) = o;
        }
    }
    __syncthreads();
    bf16x8_t qf[4][2];
    #pragma unroll
    for (int qt = 0; qt < 4; qt++)
        #pragma unroll
        for (int kc = 0; kc < 2; kc++)
            qf[qt][kc] = *(const bf16x8_t*)(qstage + (size_t)h * 4096 +
                                            (size_t)(qt * 2 + kc) * 512 + lane * 8);
    __syncthreads();   // Q in regs everywhere; arena region reusable as pls

    const unsigned short* kp0 =
        ksw + ((size_t)(bh * 128 + (1 - mod) * 64) * 2) * 512 + lane * 8;
    const unsigned short* vp0 =
        vls + ((size_t)((bh * 32 + (1 - mod) * 16) * 8)) * 512 + lane * 8;
    const bf16x8_t ones8 = { 0x3F80, 0x3F80, 0x3F80, 0x3F80,
                             0x3F80, 0x3F80, 0x3F80, 0x3F80 };

    f32x4_t O[4][4] = {};
    f32x4_t accl[4] = {};

    for (int kti = 0; kti < 8; kti++) {
        const int kt = ks * 8 + kti;
        bf16x8_t kf[8], vf[8];
        #pragma unroll
        for (int i = 0; i < 8; i++) {
            kf[i] = *(const bf16x8_t*)(kp0 + (size_t)(kt * 8 + i) * 512);
            vf[i] = *(const bf16x8_t*)(vp0 + (size_t)(kt * 8 + i) * 512);
        }
        // process q-tiles in pairs; pls holds only the live pair
        #pragma unroll
        for (int qp = 0; qp < 2; qp++) {
            f32x4_t ST[2][4];
            #pragma unroll
            for (int qtl = 0; qtl < 2; qtl++) {
                const int qt = qp * 2 + qtl;
                #pragma unroll
                for (int nb = 0; nb < 4; nb++) {
                    f32x4_t sA = {};
                    sA = MFMA32(kf[nb * 2 + 0], qf[qt][0], sA);
                    sA = MFMA32(kf[nb * 2 + 1], qf[qt][1], sA);
                    ST[qtl][nb] = sA;
                }
            }
            // exp2 -> P into LDS K32 A-frag layout (same-wave, no barrier)
            #pragma unroll
            for (int qtl = 0; qtl < 2; qtl++)
                #pragma unroll
                for (int nb = 0; nb < 4; nb++) {
                    u16x4_t pk = pk4(fast_exp2(ST[qtl][nb][0]), fast_exp2(ST[qtl][nb][1]),
                                     fast_exp2(ST[qtl][nb][2]), fast_exp2(ST[qtl][nb][3]));
                    *(u16x4_t*)(pw + qtl * 1024 + (nb >> 1) * 512 +
                                (((nb & 1) * 2 + (quad >> 1)) * 16 + col) * 8 + (quad & 1) * 4) = pk;
                }
            // P K32 A-frags -> l + PV (all MFMA32)
            #pragma unroll
            for (int qtl = 0; qtl < 2; qtl++) {
                const int qt = qp * 2 + qtl;
                bf16x8_t pf0 = *(const bf16x8_t*)(pw + qtl * 1024 + lane * 8);
                bf16x8_t pf1 = *(const bf16x8_t*)(pw + qtl * 1024 + 512 + lane * 8);
                accl[qt] = MFMA32(pf0, ones8, accl[qt]);
                accl[qt] = MFMA32(pf1, ones8, accl[qt]);
                #pragma unroll
                for (int dt = 0; dt < 4; dt++) {
                    O[qt][dt] = MFMA32(pf0, vf[dt * 2 + 0], O[qt][dt]);
                    O[qt][dt] = MFMA32(pf1, vf[dt * 2 + 1], O[qt][dt]);
                }
            }
        }
    }
    __syncthreads();   // all waves done with pls; arena reusable for combine

    // ---- key-split combine (pure add; per-head sequential fp32 LDS)
    #pragma unroll
    for (int hp = 0; hp < 2; hp++) {
        if (h == hp && ks == 1) {
            #pragma unroll
            for (int qt = 0; qt < 4; qt++)
                #pragma unroll
                for (int r = 0; r < 4; r++) {
                    int qrow = qt * 16 + quad * 4 + r;
                    #pragma unroll
                    for (int dt = 0; dt < 4; dt++)
                        Ocomb[qrow * 68 + dt * 16 + col] = O[qt][dt][r];
                    if (col == 0) lcomb[qrow] = accl[qt][r];
                }
        }
        __syncthreads();
        if (h == hp && ks == 0) {
            #pragma unroll
            for (int qt = 0; qt < 4; qt++)
                #pragma unroll
                for (int r = 0; r < 4; r++) {
                    int qrow = qt * 16 + quad * 4 + r;
                    float lt = accl[qt][r] + lcomb[qrow];
                    float rl = 1.0f / lt;
                    #pragma unroll
                    for (int dt = 0; dt < 4; dt++) {
                        float ov = O[qt][dt][r] + Ocomb[qrow * 68 + dt * 16 + col];
                        rows[qrow * 136 + hp * 64 + dt * 16 + col] = f2bf(ov * rl);
                    }
                }
        }
        __syncthreads();
    }

    // ---- out-proj: wave w -> q-tile w (16 queries, all 128 features)
    {
        const int qt2 = w;
        bf16x8_t ob[4];
        #pragma unroll
        for (int kc = 0; kc < 4; kc++)
            ob[kc] = *(const bf16x8_t*)(rows + (size_t)(qt2 * 16 + col) * 136 + kc * 32 + quad * 8);
        f32x4_t acc[8];
        #pragma unroll
        for (int j = 0; j < 8; j++) acc[j] = f32x4_t{};
        #pragma unroll
        for (int kc = 0; kc < 4; kc++)
            #pragma unroll
            for (int j = 0; j < 8; j++) {
                bf16x8_t wf = *(const bf16x8_t*)(projWs + (size_t)(j * 4 + kc) * 512 + lane * 8);
                acc[j] = MFMA32(wf, ob[kc], acc[j]);
            }
        const int n = b * 8192 + qbase + qt2 * 16 + col;
        #pragma unroll
        for (int j = 0; j < 8; j++) {
            int f0 = j * 16 + quad * 4;
            float4 bs = *(const float4*)(projb + f0);
            float4 o = { acc[j][0] + bs.x, acc[j][1] + bs.y,
                         acc[j][2] + bs.z, acc[j][3] + bs.w };
            *(float4*)(out + (size_t)n * 128 + f0) = o;
        }
    }
}

// ---------------------------------------------------------------------------
extern "C" void kernel_launch(void* const* d_in, const int* in_sizes, int n_in,
                              void* d_out, int out_size, void* d_ws, size_t ws_size,
                              hipStream_t stream) {
    const float* x     = (const float*)d_in[0];
    const float* qW    = (const float*)d_in[1];
    const float* qb    = (const float*)d_in[2];
    const float* kvW   = (const float*)d_in[3];
    const float* kvb   = (const float*)d_in[4];
    const float* projW = (const float*)d_in[5];
    const float* projb = (const float*)d_in[6];
    const float* srW   = (const float*)d_in[7];
    const float* srb   = (const float*)d_in[8];
    const float* lnW   = (const float*)d_in[9];
    const float* lnB   = (const float*)d_in[10];

    char* ws = (char*)d_ws;
    unsigned short* qWs    = (unsigned short*)(ws + 0);         // 32 KB
    unsigned short* kvWs   = (unsigned short*)(ws + 32768);     // 64 KB
    unsigned short* projWs = (unsigned short*)(ws + 98304);     // 32 KB
    unsigned short* srWs   = (unsigned short*)(ws + 131072);    // 128 KB
    unsigned short* ksw    = (unsigned short*)(ws + 262144);    // 2 MB
    unsigned short* vls    = (unsigned short*)(ws + 2359296);   // 2 MB

    k_prep_w<<<dim3(512), dim3(256), 0, stream>>>(qW, kvW, projW, srW,
                                                  qWs, kvWs, projWs, srWs);
    k_convkv<<<dim3(512), dim3(256), 0, stream>>>(x, srWs, srb, lnW, lnB,
                                                  kvWs, kvb, ksw, vls);
    k_attn_f10<<<dim3(64, 2, 4), dim3(256), 0, stream>>>(x, qWs, qb, ksw, vls,
                                                         projWs, projb, (float*)d_out);
}

// Round 15
// 129.337 us; speedup vs baseline: 1.9244x; 1.0264x over previous
//
#include <hip/hip_runtime.h>
#include <hip/hip_bf16.h>

#define LN_EPS 1e-5f

typedef __attribute__((ext_vector_type(8))) short bf16x8_t;
typedef __attribute__((ext_vector_type(4))) float f32x4_t;
typedef __attribute__((ext_vector_type(4))) unsigned short u16x4_t;

#define MFMA32(a, b, c) __builtin_amdgcn_mfma_f32_16x16x32_bf16(a, b, c, 0, 0, 0)

// Guaranteed-native exp2 (single v_exp_f32) — verified win in R9.
__device__ inline float fast_exp2(float x) {
#if __has_builtin(__builtin_amdgcn_exp2f)
    return __builtin_amdgcn_exp2f(x);
#else
    float r;
    asm volatile("v_exp_f32 %0, %1\n\ts_nop 0" : "=v"(r) : "v"(x));
    return r;
#endif
}

__device__ inline unsigned short f2bf(float f) {
    union { float f; unsigned int u; } v; v.f = f;
    unsigned int r = v.u + 0x7fffu + ((v.u >> 16) & 1u);
    return (unsigned short)(r >> 16);
}

__device__ inline u16x4_t pk4(float a, float b, float c, float d) {
    union { u16x4_t v; __hip_bfloat162 h[2]; } u;
    u.h[0] = __float22bfloat162_rn(float2{a, b});
    u.h[1] = __float22bfloat162_rn(float2{c, d});
    return u.v;
}
__device__ inline bf16x8_t pk8(float4 a, float4 b) {
    union { bf16x8_t v; __hip_bfloat162 h[4]; } u;
    u.h[0] = __float22bfloat162_rn(float2{a.x, a.y});
    u.h[1] = __float22bfloat162_rn(float2{a.z, a.w});
    u.h[2] = __float22bfloat162_rn(float2{b.x, b.y});
    u.h[3] = __float22bfloat162_rn(float2{b.z, b.w});
    return u.v;
}

// Fragment-layout index for [ROWS][KD] stored as MFMA fragments:
// tile (row>>4, k>>5) = 512 contiguous u16; lane=((k>>3)&3)*16+(row&15), j=k&7.
__device__ inline size_t fragidx(int row, int k, int KC) {
    return ((size_t)((row >> 4) * KC + (k >> 5))) * 512 +
           (((k >> 3) & 3) * 16 + (row & 15)) * 8 + (k & 7);
}

// ---------------------------------------------------------------------------
__global__ void k_prep_w(const float* __restrict__ qW, const float* __restrict__ kvW,
                         const float* __restrict__ projW, const float* __restrict__ srW,
                         unsigned short* __restrict__ qWs, unsigned short* __restrict__ kvWs,
                         unsigned short* __restrict__ projWs, unsigned short* __restrict__ srWs) {
    int i = blockIdx.x * 256 + threadIdx.x;
    if (i < 16384) {
        int n = i & 127, k = i >> 7;
        qWs[fragidx(n, k, 4)] = f2bf(qW[k * 128 + n]);
    } else if (i < 49152) {
        int j = i - 16384; int n = j & 255, k = j >> 8;
        kvWs[fragidx(n, k, 4)] = f2bf(kvW[k * 256 + n]);
    } else if (i < 65536) {
        int j = i - 49152; int n = j & 127, k = j >> 7;
        projWs[fragidx(n, k, 4)] = f2bf(projW[k * 128 + n]);
    } else {
        int j = i - 65536; int n = j >> 9, rem = j & 511, q = rem >> 7, c = rem & 127;
        srWs[fragidx(n, q * 128 + c, 16)] = f2bf(srW[n * 512 + c * 4 + q]);
    }
}

// ---------------------------------------------------------------------------
// Fused SR-conv + bias + LayerNorm + kv-projection (unchanged from R14).
#define XPAD 132
__global__ __launch_bounds__(256)
void k_convkv(const float* __restrict__ x, const unsigned short* __restrict__ srWs,
              const float* __restrict__ srb, const float* __restrict__ lnW,
              const float* __restrict__ lnB, const unsigned short* __restrict__ kvWs,
              const float* __restrict__ kvb, unsigned short* __restrict__ ksw,
              unsigned short* __restrict__ vls) {
    const int t = threadIdx.x, w = t >> 6, lane = t & 63;
    const int col = lane & 15, quad = lane >> 4;
    const int RT = blockIdx.x;

    __shared__ unsigned short xl[64 * XPAD];
    __shared__ unsigned short xs[4 * 512];
    __shared__ float lnred[4][16][2];

    const int pb = RT >> 7, phf = (RT >> 6) & 1;
    const int oy = (RT >> 1) & 31, ox0 = (RT & 1) * 16;
    const int n0 = phf * 4096 + 2 * oy * 64 + 2 * ox0;
    #pragma unroll
    for (int it = 0; it < 8; it++) {
        int idx = it * 256 + t;
        int chunk = idx >> 10;
        int rr = (idx >> 5) & 31;
        int c4 = idx & 31;
        float4 v = *(const float4*)(x + ((size_t)(pb * 8192 + n0 + chunk * 64 + rr)) * 128 + c4 * 4);
        *(u16x4_t*)(xl + (chunk * 32 + rr) * XPAD + c4 * 4) = pk4(v.x, v.y, v.z, v.w);
    }
    __syncthreads();

    f32x4_t acc[2] = {};
    {
        const unsigned short* wp = srWs + lane * 8;
        #pragma unroll
        for (int kc = 0; kc < 16; kc++) {
            const int q = kc >> 2, cg = kc & 3;
            const int r = (q >> 1) * 32 + 2 * col + (q & 1);
            bf16x8_t xb = *(const bf16x8_t*)(xl + r * XPAD + cg * 32 + quad * 8);
            #pragma unroll
            for (int jj = 0; jj < 2; jj++) {
                bf16x8_t wf = *(const bf16x8_t*)(wp + (size_t)((w * 2 + jj) * 16 + kc) * 512);
                acc[jj] = MFMA32(wf, xb, acc[jj]);
            }
        }
    }
    float s = 0.f, ss = 0.f;
    #pragma unroll
    for (int jj = 0; jj < 2; jj++) {
        float4 bs = *(const float4*)(srb + (w * 2 + jj) * 16 + quad * 4);
        acc[jj][0] += bs.x; acc[jj][1] += bs.y; acc[jj][2] += bs.z; acc[jj][3] += bs.w;
        #pragma unroll
        for (int r = 0; r < 4; r++) { float v = acc[jj][r]; s += v; ss += v * v; }
    }
    s += __shfl_xor(s, 16, 64);  s += __shfl_xor(s, 32, 64);
    ss += __shfl_xor(ss, 16, 64); ss += __shfl_xor(ss, 32, 64);
    if (lane < 16) { lnred[w][lane][0] = s; lnred[w][lane][1] = ss; }
    __syncthreads();
    float stot = 0.f, sstot = 0.f;
    #pragma unroll
    for (int ww = 0; ww < 4; ww++) { stot += lnred[ww][col][0]; sstot += lnred[ww][col][1]; }
    float mean = stot * (1.0f / 128.0f);
    float var = sstot * (1.0f / 128.0f) - mean * mean;
    float rs = rsqrtf(var + LN_EPS);
    #pragma unroll
    for (int jj = 0; jj < 2; jj++) {
        int f0 = (w * 2 + jj) * 16 + quad * 4;
        float4 g = *(const float4*)(lnW + f0);
        float4 be = *(const float4*)(lnB + f0);
        u16x4_t o = pk4((acc[jj][0] - mean) * rs * g.x + be.x,
                        (acc[jj][1] - mean) * rs * g.y + be.y,
                        (acc[jj][2] - mean) * rs * g.z + be.z,
                        (acc[jj][3] - mean) * rs * g.w + be.w);
        *(u16x4_t*)(xs + ((size_t)(f0 >> 5)) * 512 +
                    (((f0 >> 3) & 3) * 16 + col) * 8 + (f0 & 7)) = o;
    }
    __syncthreads();
    bf16x8_t xf[4];
    #pragma unroll
    for (int kc = 0; kc < 4; kc++)
        xf[kc] = *(const bf16x8_t*)(xs + (size_t)kc * 512 + lane * 8);
    const int p0 = RT * 16;
    const int bb = p0 >> 11;
    #pragma unroll
    for (int jj = 0; jj < 2; jj++) {
        const int nt = w * 2 + jj;
        f32x4_t aK = {};
        #pragma unroll
        for (int kc = 0; kc < 4; kc++) {
            bf16x8_t wf = *(const bf16x8_t*)(kvWs + (size_t)(nt * 4 + kc) * 512 + lane * 8);
            aK = MFMA32(wf, xf[kc], aK);
        }
        float4 bs = *(const float4*)(kvb + nt * 16 + quad * 4);
        int m = (p0 + col) & 2047;
        int bh = bb * 2 + (nt >> 2);
        int d0 = (nt & 3) * 16 + quad * 4;
        u16x4_t o = pk4(aK[0] + bs.x, aK[1] + bs.y, aK[2] + bs.z, aK[3] + bs.w);
        *(u16x4_t*)(ksw + ((size_t)(bh * 128 + (m >> 4)) * 2 + (d0 >> 5)) * 512 +
                    (((d0 >> 3) & 3) * 16 + (m & 15)) * 8 + (d0 & 7)) = o;
    }
    #pragma unroll
    for (int jj = 0; jj < 2; jj++) {
        const int nt = w * 2 + jj;
        f32x4_t aV = {};
        #pragma unroll
        for (int kc = 0; kc < 4; kc++) {
            bf16x8_t wf = *(const bf16x8_t*)(kvWs + (size_t)((8 + nt) * 4 + kc) * 512 + lane * 8);
            aV = MFMA32(xf[kc], wf, aV);
        }
        int fv = nt * 16 + col;
        int h = fv >> 6, dd = fv & 63;
        float bv = kvb[128 + fv];
        int m0 = (p0 + quad * 4) & 2047;
        int bh = bb * 2 + h;
        int kt = m0 >> 6;
        int tt = (m0 >> 5) & 1;
        int base = m0 & 31;
        int quad_b = base >> 3, j0 = base & 7;
        u16x4_t o = pk4(aV[0] + bv, aV[1] + bv, aV[2] + bv, aV[3] + bv);
        *(u16x4_t*)(vls + (((size_t)((bh * 32 + kt) * 4 + (dd >> 4)) * 2 + tt) * 512) +
                    (quad_b * 16 + (dd & 15)) * 8 + j0) = o;
    }
}

// ---------------------------------------------------------------------------
// Fused q-proj + attention + out-proj. R14 structure (64 q/wave key-split,
// all-MFMA32, native exp2, aliased LDS arena) + register K/V double-buffer
// (R10's verified pattern) + qp-interleaved software pipeline: S(qp1) MFMAs
// issue between P(qp0)'s LDS write and read, filling the lgkm latency.
// Block 256 = 4 waves (ks=w&1, h=w>>1); grid (64, 2, 4) = 512 blocks.
__global__ __launch_bounds__(256, 2)
void k_attn_f11(const float* __restrict__ x, const unsigned short* __restrict__ qWs,
                const float* __restrict__ qb, const unsigned short* __restrict__ ksw,
                const unsigned short* __restrict__ vls, const unsigned short* __restrict__ projWs,
                const float* __restrict__ projb, float* __restrict__ out) {
    const int blkx = blockIdx.x, mod = blockIdx.y, b = blockIdx.z;
    const int t = threadIdx.x, w = t >> 6, lane = t & 63;
    const int col = lane & 15, quad = lane >> 4;
    const int ks = w & 1, h = w >> 1;
    const int bh = b * 2 + h;
    const int qbase = mod * 4096 + blkx * 64;      // 64 queries per block

    __shared__ char arena[35200];
    unsigned short* qstage = (unsigned short*)arena;            // [0, 16K)
    unsigned short* pw     = (unsigned short*)arena + w * 2048; // pls, 4KB/wave
    unsigned short* rows   = (unsigned short*)arena;            // [0, 17.4K)
    float* Ocomb = (float*)(arena + 17536);                     // 64*68*4 B
    float* lcomb = (float*)(arena + 34944);                     // 256 B

    // ---- q-proj: wave (ks,h) computes q-tiles {2ks, 2ks+1} of head h
    const float sc = 0.125f * 1.44269504089f;
    #pragma unroll
    for (int qtl = 0; qtl < 2; qtl++) {
        const int qt = ks * 2 + qtl;
        const float* xrow = x + ((size_t)b * 8192 + qbase + qt * 16 + col) * 128;
        f32x4_t acc[4] = {};
        #pragma unroll
        for (int kc = 0; kc < 4; kc++) {
            float4 xa = *(const float4*)(xrow + kc * 32 + quad * 8);
            float4 xb2 = *(const float4*)(xrow + kc * 32 + quad * 8 + 4);
            bf16x8_t xf = pk8(xa, xb2);
            #pragma unroll
            for (int j = 0; j < 4; j++) {
                bf16x8_t wf = *(const bf16x8_t*)(qWs + (size_t)((h * 4 + j) * 4 + kc) * 512 + lane * 8);
                acc[j] = MFMA32(wf, xf, acc[j]);
            }
        }
        #pragma unroll
        for (int j = 0; j < 4; j++) {
            float4 bs = *(const float4*)(qb + h * 64 + j * 16 + quad * 4);
            u16x4_t o = pk4((acc[j][0] + bs.x) * sc, (acc[j][1] + bs.y) * sc,
                            (acc[j][2] + bs.z) * sc, (acc[j][3] + bs.w) * sc);
            *(u16x4_t*)(qstage + (size_t)h * 4096 + ((size_t)(qt * 2 + (j >> 1))) * 512 +
                        (((j & 1) * 2 + (quad >> 1)) * 16 + col) * 8 + (quad & 1) * 4) = o;
        }
    }
    __syncthreads();
    bf16x8_t qf[4][2];
    #pragma unroll
    for (int qt = 0; qt < 4; qt++)
        #pragma unroll
        for (int kc = 0; kc < 2; kc++)
            qf[qt][kc] = *(const bf16x8_t*)(qstage + (size_t)h * 4096 +
                                            (size_t)(qt * 2 + kc) * 512 + lane * 8);
    __syncthreads();   // Q in regs everywhere; arena region reusable as pls

    const unsigned short* kp0 =
        ksw + ((size_t)(bh * 128 + (1 - mod) * 64) * 2) * 512 + lane * 8;
    const unsigned short* vp0 =
        vls + ((size_t)((bh * 32 + (1 - mod) * 16) * 8)) * 512 + lane * 8;
    const bf16x8_t ones8 = { 0x3F80, 0x3F80, 0x3F80, 0x3F80,
                             0x3F80, 0x3F80, 0x3F80, 0x3F80 };

    f32x4_t O[4][4] = {};
    f32x4_t accl[4] = {};

    bf16x8_t kfA[8], vfA[8], kfB[8], vfB[8];
    const int ktbase = ks * 8;

    auto prefA = [&](int kt) {
        #pragma unroll
        for (int i = 0; i < 8; i++) {
            kfA[i] = *(const bf16x8_t*)(kp0 + (size_t)(kt * 8 + i) * 512);
            vfA[i] = *(const bf16x8_t*)(vp0 + (size_t)(kt * 8 + i) * 512);
        }
    };
    auto prefB = [&](int kt) {
        #pragma unroll
        for (int i = 0; i < 8; i++) {
            kfB[i] = *(const bf16x8_t*)(kp0 + (size_t)(kt * 8 + i) * 512);
            vfB[i] = *(const bf16x8_t*)(vp0 + (size_t)(kt * 8 + i) * 512);
        }
    };
    // qp-interleaved body: S(qp1) issues between P(qp0) write and read.
    auto body = [&](bf16x8_t (&kfc)[8], bf16x8_t (&vfc)[8]) {
        // S for qp0 (q-tiles 0,1)
        f32x4_t ST0[2][4];
        #pragma unroll
        for (int qtl = 0; qtl < 2; qtl++)
            #pragma unroll
            for (int nb = 0; nb < 4; nb++) {
                f32x4_t sA = {};
                sA = MFMA32(kfc[nb * 2 + 0], qf[qtl][0], sA);
                sA = MFMA32(kfc[nb * 2 + 1], qf[qtl][1], sA);
                ST0[qtl][nb] = sA;
            }
        // exp2 -> P(qp0) into LDS
        #pragma unroll
        for (int qtl = 0; qtl < 2; qtl++)
            #pragma unroll
            for (int nb = 0; nb < 4; nb++) {
                u16x4_t pk = pk4(fast_exp2(ST0[qtl][nb][0]), fast_exp2(ST0[qtl][nb][1]),
                                 fast_exp2(ST0[qtl][nb][2]), fast_exp2(ST0[qtl][nb][3]));
                *(u16x4_t*)(pw + qtl * 1024 + (nb >> 1) * 512 +
                            (((nb & 1) * 2 + (quad >> 1)) * 16 + col) * 8 + (quad & 1) * 4) = pk;
            }
        // S for qp1 (q-tiles 2,3) — independent MFMAs fill the LDS wait
        f32x4_t ST1[2][4];
        #pragma unroll
        for (int qtl = 0; qtl < 2; qtl++)
            #pragma unroll
            for (int nb = 0; nb < 4; nb++) {
                f32x4_t sA = {};
                sA = MFMA32(kfc[nb * 2 + 0], qf[2 + qtl][0], sA);
                sA = MFMA32(kfc[nb * 2 + 1], qf[2 + qtl][1], sA);
                ST1[qtl][nb] = sA;
            }
        // read P(qp0) -> l + PV
        #pragma unroll
        for (int qtl = 0; qtl < 2; qtl++) {
            bf16x8_t pf0 = *(const bf16x8_t*)(pw + qtl * 1024 + lane * 8);
            bf16x8_t pf1 = *(const bf16x8_t*)(pw + qtl * 1024 + 512 + lane * 8);
            accl[qtl] = MFMA32(pf0, ones8, accl[qtl]);
            accl[qtl] = MFMA32(pf1, ones8, accl[qtl]);
            #pragma unroll
            for (int dt = 0; dt < 4; dt++) {
                O[qtl][dt] = MFMA32(pf0, vfc[dt * 2 + 0], O[qtl][dt]);
                O[qtl][dt] = MFMA32(pf1, vfc[dt * 2 + 1], O[qtl][dt]);
            }
        }
        // exp2 -> P(qp1) into the same slots (after qp0 reads; same-wave order)
        #pragma unroll
        for (int qtl = 0; qtl < 2; qtl++)
            #pragma unroll
            for (int nb = 0; nb < 4; nb++) {
                u16x4_t pk = pk4(fast_exp2(ST1[qtl][nb][0]), fast_exp2(ST1[qtl][nb][1]),
                                 fast_exp2(ST1[qtl][nb][2]), fast_exp2(ST1[qtl][nb][3]));
                *(u16x4_t*)(pw + qtl * 1024 + (nb >> 1) * 512 +
                            (((nb & 1) * 2 + (quad >> 1)) * 16 + col) * 8 + (quad & 1) * 4) = pk;
            }
        // read P(qp1) -> l + PV
        #pragma unroll
        for (int qtl = 0; qtl < 2; qtl++) {
            const int qt = 2 + qtl;
            bf16x8_t pf0 = *(const bf16x8_t*)(pw + qtl * 1024 + lane * 8);
            bf16x8_t pf1 = *(const bf16x8_t*)(pw + qtl * 1024 + 512 + lane * 8);
            accl[qt] = MFMA32(pf0, ones8, accl[qt]);
            accl[qt] = MFMA32(pf1, ones8, accl[qt]);
            #pragma unroll
            for (int dt = 0; dt < 4; dt++) {
                O[qt][dt] = MFMA32(pf0, vfc[dt * 2 + 0], O[qt][dt]);
                O[qt][dt] = MFMA32(pf1, vfc[dt * 2 + 1], O[qt][dt]);
            }
        }
    };

    prefA(ktbase);
    #pragma unroll
    for (int kt2 = 0; kt2 < 4; kt2++) {
        prefB(ktbase + kt2 * 2 + 1);               // in flight across body(A)
        body(kfA, vfA);
        if (kt2 < 3) prefA(ktbase + kt2 * 2 + 2);  // in flight across body(B)
        body(kfB, vfB);
    }
    __syncthreads();   // all waves done with pls; arena reusable for combine

    // ---- key-split combine (pure add; per-head sequential fp32 LDS)
    #pragma unroll
    for (int hp = 0; hp < 2; hp++) {
        if (h == hp && ks == 1) {
            #pragma unroll
            for (int qt = 0; qt < 4; qt++)
                #pragma unroll
                for (int r = 0; r < 4; r++) {
                    int qrow = qt * 16 + quad * 4 + r;
                    #pragma unroll
                    for (int dt = 0; dt < 4; dt++)
                        Ocomb[qrow * 68 + dt * 16 + col] = O[qt][dt][r];
                    if (col == 0) lcomb[qrow] = accl[qt][r];
                }
        }
        __syncthreads();
        if (h == hp && ks == 0) {
            #pragma unroll
            for (int qt = 0; qt < 4; qt++)
                #pragma unroll
                for (int r = 0; r < 4; r++) {
                    int qrow = qt * 16 + quad * 4 + r;
                    float lt = accl[qt][r] + lcomb[qrow];
                    float rl = 1.0f / lt;
                    #pragma unroll
                    for (int dt = 0; dt < 4; dt++) {
                        float ov = O[qt][dt][r] + Ocomb[qrow * 68 + dt * 16 + col];
                        rows[qrow * 136 + hp * 64 + dt * 16 + col] = f2bf(ov * rl);
                    }
                }
        }
        __syncthreads();
    }

    // ---- out-proj: wave w -> q-tile w (16 queries, all 128 features)
    {
        const int qt2 = w;
        bf16x8_t ob[4];
        #pragma unroll
        for (int kc = 0; kc < 4; kc++)
            ob[kc] = *(const bf16x8_t*)(rows + (size_t)(qt2 * 16 + col) * 136 + kc * 32 + quad * 8);
        f32x4_t acc[8];
        #pragma unroll
        for (int j = 0; j < 8; j++) acc[j] = f32x4_t{};
        #pragma unroll
        for (int kc = 0; kc < 4; kc++)
            #pragma unroll
            for (int j = 0; j < 8; j++) {
                bf16x8_t wf = *(const bf16x8_t*)(projWs + (size_t)(j * 4 + kc) * 512 + lane * 8);
                acc[j] = MFMA32(wf, ob[kc], acc[j]);
            }
        const int n = b * 8192 + qbase + qt2 * 16 + col;
        #pragma unroll
        for (int j = 0; j < 8; j++) {
            int f0 = j * 16 + quad * 4;
            float4 bs = *(const float4*)(projb + f0);
            float4 o = { acc[j][0] + bs.x, acc[j][1] + bs.y,
                         acc[j][2] + bs.z, acc[j][3] + bs.w };
            *(float4*)(out + (size_t)n * 128 + f0) = o;
        }
    }
}

// ---------------------------------------------------------------------------
extern "C" void kernel_launch(void* const* d_in, const int* in_sizes, int n_in,
                              void* d_out, int out_size, void* d_ws, size_t ws_size,
                              hipStream_t stream) {
    const float* x     = (const float*)d_in[0];
    const float* qW    = (const float*)d_in[1];
    const float* qb    = (const float*)d_in[2];
    const float* kvW   = (const float*)d_in[3];
    const float* kvb   = (const float*)d_in[4];
    const float* projW = (const float*)d_in[5];
    const float* projb = (const float*)d_in[6];
    const float* srW   = (const float*)d_in[7];
    const float* srb   = (const float*)d_in[8];
    const float* lnW   = (const float*)d_in[9];
    const float* lnB   = (const float*)d_in[10];

    char* ws = (char*)d_ws;
    unsigned short* qWs    = (unsigned short*)(ws + 0);         // 32 KB
    unsigned short* kvWs   = (unsigned short*)(ws + 32768);     // 64 KB
    unsigned short* projWs = (unsigned short*)(ws + 98304);     // 32 KB
    unsigned short* srWs   = (unsigned short*)(ws + 131072);    // 128 KB
    unsigned short* ksw    = (unsigned short*)(ws + 262144);    // 2 MB
    unsigned short* vls    = (unsigned short*)(ws + 2359296);   // 2 MB

    k_prep_w<<<dim3(512), dim3(256), 0, stream>>>(qW, kvW, projW, srW,
                                                  qWs, kvWs, projWs, srWs);
    k_convkv<<<dim3(512), dim3(256), 0, stream>>>(x, srWs, srb, lnW, lnB,
                                                  kvWs, kvb, ksw, vls);
    k_attn_f11<<<dim3(64, 2, 4), dim3(256), 0, stream>>>(x, qWs, qb, ksw, vls,
                                                         projWs, projb, (float*)d_out);
}